// Round 2
// baseline (208.739 us; speedup 1.0000x reference)
//
#include <hip/hip_runtime.h>

#define BTOT 1048576
#define D 17
#define H 8
#define OUT 6
#define E 4
#define G1 64
#define G2 32

typedef float v2f __attribute__((ext_vector_type(2)));
typedef float v4f __attribute__((ext_vector_type(4)));

// packed fp32 FMA: acc.{x,y} += w.{x,y} * v.{x,y}
// weights are wave-uniform -> SGPR-pair operand (1 scalar operand allowed)
#define PKFMA_S(acc, w, vv) \
    asm("v_pk_fma_f32 %0, %1, %2, %0" : "+v"(acc) : "s"(w), "v"(vv))
// per-lane weights (from LDS) -> VGPR operand
#define PKFMA_V(acc, w, vv) \
    asm("v_pk_fma_f32 %0, %1, %2, %0" : "+v"(acc) : "v"(w), "v"(vv))

// Per-expert LDS stride in dwords. 296 % 32 == 8 -> expert blocks start on
// bank groups {0,8,16,24}: divergent-sel gathers are bank-disjoint.
#define WSTR 296
// layout within an expert block (dword offsets):
//   [0..135]   eW1  (i*8 + h)   [136..143] eb1
//   [144..207] eW2  (k*8 + h)   [208..215] eb2
//   [216..279] eW3  rows padded to 8 (k*8 + o, o<6 valid)
//   [280..285] eb3  [286..295] pad

__global__ __launch_bounds__(256) void hybrid_ruc_kernel(
    const float* __restrict__ x,
    const float* __restrict__ eW1, const float* __restrict__ eb1,
    const float* __restrict__ eW2, const float* __restrict__ eb2,
    const float* __restrict__ eW3, const float* __restrict__ eb3,
    const float* __restrict__ gW1, const float* __restrict__ gb1,
    const float* __restrict__ gW2, const float* __restrict__ gb2,
    const float* __restrict__ gW3, const float* __restrict__ gb3,
    float* __restrict__ out)
{
    __shared__ float sx[256 * D];
    __shared__ __align__(16) float swl[E * WSTR];

    const int tid = threadIdx.x;
    const long long bbase = (long long)blockIdx.x * 256;

    // ---- stage this block's x rows into LDS (coalesced) ----
    #pragma unroll
    for (int k = 0; k < D; ++k) {
        int t = tid + k * 256;
        sx[t] = x[bbase * D + t];
    }

    // ---- stage expert weights into LDS (bank-group layout) ----
    for (int t = tid; t < E * D * H; t += 256) {          // eW1: 544
        swl[(t / 136) * WSTR + (t % 136)] = eW1[t];
    }
    if (tid < E * H * H) {                                 // eW2: 256
        swl[(tid / 64) * WSTR + 144 + (tid % 64)] = eW2[tid];
    }
    if (tid < E * H * OUT) {                               // eW3: 192, rows padded to 8
        int e = tid / 48, r = tid % 48, k = r / 6, o = r % 6;
        swl[e * WSTR + 216 + k * 8 + o] = eW3[tid];
    }
    if (tid < E * H) {                                     // eb1: 32
        swl[(tid / 8) * WSTR + 136 + (tid % 8)] = eb1[tid];
    }
    if (tid < E * H) {                                     // eb2: 32
        swl[(tid / 8) * WSTR + 208 + (tid % 8)] = eb2[tid];
    }
    if (tid < E * OUT) {                                   // eb3: 24
        swl[(tid / 6) * WSTR + 280 + (tid % 6)] = eb3[tid];
    }
    __syncthreads();

    // per-thread x row (stride-17 LDS read: 2-way bank alias, free)
    float xr[D];
    #pragma unroll
    for (int i = 0; i < D; ++i) xr[i] = sx[tid * D + i];

    // ---- gating layer1 (17->64) + layer2 (64->32), fused, tiled, packed ----
    v2f h2p[16];
    #pragma unroll
    for (int j2 = 0; j2 < 16; ++j2)
        h2p[j2] = *(const v2f*)(gb2 + 2 * j2);

    #pragma unroll 1
    for (int jt = 0; jt < G1 / 16; ++jt) {      // 4 tiles of 16 hidden units
        v2f h1p[8];
        #pragma unroll
        for (int c2 = 0; c2 < 8; ++c2)
            h1p[c2] = *(const v2f*)(gb1 + jt * 16 + 2 * c2);

        #pragma unroll
        for (int i = 0; i < D; ++i) {
            const float xi = xr[i];
            const v2f xi2 = {xi, xi};
            const float* w1row = gW1 + i * G1 + jt * 16;   // uniform -> s_load
            #pragma unroll
            for (int c2 = 0; c2 < 8; ++c2) {
                const v2f w = *(const v2f*)(w1row + 2 * c2);
                PKFMA_S(h1p[c2], w, xi2);
            }
        }

        #pragma unroll
        for (int c2 = 0; c2 < 8; ++c2) {
            #pragma unroll
            for (int half = 0; half < 2; ++half) {
                const float hv = fmaxf(half ? h1p[c2].y : h1p[c2].x, 0.0f);
                const v2f hv2 = {hv, hv};
                const float* w2row = gW2 + (jt * 16 + c2 * 2 + half) * G2; // uniform
                #pragma unroll
                for (int j2 = 0; j2 < 16; ++j2) {
                    const v2f w = *(const v2f*)(w2row + 2 * j2);
                    PKFMA_S(h2p[j2], w, hv2);
                }
            }
        }
    }

    // ---- gating layer3 (32->4), packed ----
    v2f lg01 = *(const v2f*)(gb3);
    v2f lg23 = *(const v2f*)(gb3 + 2);
    #pragma unroll
    for (int j2 = 0; j2 < 16; ++j2) {
        #pragma unroll
        for (int half = 0; half < 2; ++half) {
            const int j = j2 * 2 + half;
            const float hv = fmaxf(half ? h2p[j2].y : h2p[j2].x, 0.0f);
            const v2f hv2 = {hv, hv};
            const v2f wa = *(const v2f*)(gW3 + j * E);      // uniform
            const v2f wb = *(const v2f*)(gW3 + j * E + 2);
            PKFMA_S(lg01, wa, hv2);
            PKFMA_S(lg23, wb, hv2);
        }
    }

    const float lg0 = lg01.x, lg1 = lg01.y, lg2 = lg23.x, lg3 = lg23.y;

    // ---- argmax, first-max-wins (matches jnp.argmax) ----
    int sel = 0;
    float best = lg0;
    if (lg1 > best) { best = lg1; sel = 1; }
    if (lg2 > best) { best = lg2; sel = 2; }
    if (lg3 > best) { best = lg3; sel = 3; }

    // ---- compute ONLY the selected expert; weights gathered from LDS ----
    const float* wl = &swl[sel * WSTR];        // per-lane base, bank-disjoint by e

    v2f t1p[4];
    {
        const v4f ba = *(const v4f*)(wl + 136);
        const v4f bb = *(const v4f*)(wl + 140);
        t1p[0] = ba.xy; t1p[1] = ba.zw; t1p[2] = bb.xy; t1p[3] = bb.zw;
    }
    #pragma unroll
    for (int i = 0; i < D; ++i) {
        const float xi = xr[i];
        const v2f xi2 = {xi, xi};
        const v4f wa = *(const v4f*)(wl + i * 8);
        const v4f wb = *(const v4f*)(wl + i * 8 + 4);
        PKFMA_V(t1p[0], wa.xy, xi2);
        PKFMA_V(t1p[1], wa.zw, xi2);
        PKFMA_V(t1p[2], wb.xy, xi2);
        PKFMA_V(t1p[3], wb.zw, xi2);
    }

    v2f t2p[4];
    {
        const v4f ba = *(const v4f*)(wl + 208);
        const v4f bb = *(const v4f*)(wl + 212);
        t2p[0] = ba.xy; t2p[1] = ba.zw; t2p[2] = bb.xy; t2p[3] = bb.zw;
    }
    #pragma unroll
    for (int k2 = 0; k2 < 4; ++k2) {
        #pragma unroll
        for (int half = 0; half < 2; ++half) {
            const int k = k2 * 2 + half;
            const float tv = fmaxf(half ? t1p[k2].y : t1p[k2].x, 0.0f);
            const v2f tv2 = {tv, tv};
            const v4f wa = *(const v4f*)(wl + 144 + k * 8);
            const v4f wb = *(const v4f*)(wl + 144 + k * 8 + 4);
            PKFMA_V(t2p[0], wa.xy, tv2);
            PKFMA_V(t2p[1], wa.zw, tv2);
            PKFMA_V(t2p[2], wb.xy, tv2);
            PKFMA_V(t2p[3], wb.zw, tv2);
        }
    }

    v2f pp0, pp1, pp2;
    {
        const v4f ba = *(const v4f*)(wl + 280);
        pp0 = ba.xy; pp1 = ba.zw;
        pp2 = *(const v2f*)(wl + 284);
    }
    #pragma unroll
    for (int k2 = 0; k2 < 4; ++k2) {
        #pragma unroll
        for (int half = 0; half < 2; ++half) {
            const int k = k2 * 2 + half;
            const float tv = fmaxf(half ? t2p[k2].y : t2p[k2].x, 0.0f);
            const v2f tv2 = {tv, tv};
            const v4f wa = *(const v4f*)(wl + 216 + k * 8);      // o=0..3
            const v2f wb = *(const v2f*)(wl + 216 + k * 8 + 4);  // o=4,5
            PKFMA_V(pp0, wa.xy, tv2);
            PKFMA_V(pp1, wa.zw, tv2);
            PKFMA_V(pp2, wb, tv2);
        }
    }

    // ---- store: predictions [B,6] then gating_logits [B,4], vectorized ----
    const long long b = bbase + tid;
    *(v2f*)(out + b * 6)     = pp0;   // b*24 B: 8B-aligned
    *(v2f*)(out + b * 6 + 2) = pp1;
    *(v2f*)(out + b * 6 + 4) = pp2;
    float* lout = out + (long long)BTOT * OUT;
    const v4f lgv = {lg0, lg1, lg2, lg3};
    *(v4f*)(lout + b * 4) = lgv;      // b*16 B: 16B-aligned
}

extern "C" void kernel_launch(void* const* d_in, const int* in_sizes, int n_in,
                              void* d_out, int out_size, void* d_ws, size_t ws_size,
                              hipStream_t stream) {
    const float* x   = (const float*)d_in[0];
    const float* eW1 = (const float*)d_in[1];
    const float* eb1 = (const float*)d_in[2];
    const float* eW2 = (const float*)d_in[3];
    const float* eb2 = (const float*)d_in[4];
    const float* eW3 = (const float*)d_in[5];
    const float* eb3 = (const float*)d_in[6];
    const float* gW1 = (const float*)d_in[7];
    const float* gb1 = (const float*)d_in[8];
    const float* gW2 = (const float*)d_in[9];
    const float* gb2 = (const float*)d_in[10];
    const float* gW3 = (const float*)d_in[11];
    const float* gb3 = (const float*)d_in[12];
    float* out = (float*)d_out;

    dim3 grid(BTOT / 256), block(256);
    hipLaunchKernelGGL(hybrid_ruc_kernel, grid, block, 0, stream,
                       x, eW1, eb1, eW2, eb2, eW3, eb3,
                       gW1, gb1, gW2, gb2, gW3, gb3, out);
}